// Round 13
// baseline (63.751 us; speedup 1.0000x reference)
//
#include <hip/hip_runtime.h>

#define NBOX 4000
#define NPAD 4096
#define BATCH 8
#define WPR 64          // 64-bit words per suppression row
#define MAXK 300

typedef unsigned long long u64;

// Static device scratch (deterministic: every consulted value is rewritten
// each call; bits/rows >= nvalid are masked out before use).
__device__ u64 g_sup[BATCH][NPAD][WPR];            // ~16.8 MB full rows
__device__ u64 g_tile64[BATCH][64][64];            // diag word t of row 64t+r
__device__ u64 g_colT[BATCH][65][64];              // transposed diag blocks
__device__ float4 g_sorted[BATCH][NPAD];           // 512 KB
__device__ int g_nvalid[BATCH];

// ---------------------------------------------------------------------------
// Kernel 1: per-batch stable LSD radix sort, NOW 1024 threads x EPT=4.
// Key k = 0x3F800000 - bits(fg): valid => fg > 0.5 => k in (0, 0x800000),
// fits 24 bits -> 6 passes x 4 bits. Invalid/pad k = 0xFFFFFF sorts last.
// Blocked ownership [4t, 4t+3] + digit-major scan f = 16*tid preserves
// stability (same permutation as the proven 256-thread version).
// uint4/ushort4 LDS accesses are conflict-free (16B/8B per lane); histogram
// increments Hs[d*1088 + tid] are bank = (tid/2)%32 — 2-way, free.
// 8 blocks -> round-robin puts batch b on XCD b (matches iou/colT/nms).
// ---------------------------------------------------------------------------
#define SORT_T 1024
#define EPT 4
#define HP2 1088        // hist pitch (u16 entries per digit row)

__global__ __launch_bounds__(SORT_T) void sort_kernel(const float* __restrict__ props,
                                                      const float* __restrict__ scores) {
    const int b = blockIdx.x;
    const int tid = threadIdx.x;
    __shared__ unsigned int K0[NPAD], K1[NPAD];        // 32 KB
    __shared__ unsigned short P0[NPAD], P1[NPAD];      // 16 KB
    __shared__ unsigned short Hs[16 * HP2];            // 34 KB
    __shared__ unsigned int sWT[16];
    __shared__ int s_cnt;
    if (tid == 0) s_cnt = 0;
    __syncthreads();

    // Build keys + payloads (blocked: thread t owns n in [4t, 4t+3]).
    int localc = 0;
    {
        const int n0 = tid * EPT;
        unsigned int kk[EPT];
        #pragma unroll
        for (int e = 0; e < EPT; ++e) {
            const int n = n0 + e;
            unsigned int k = 0xFFFFFFu;
            if (n < NBOX) {
                const float2 sc = *reinterpret_cast<const float2*>(scores + ((size_t)b * NBOX + n) * 2);
                const float4 p  = *reinterpret_cast<const float4*>(props  + ((size_t)b * NBOX + n) * 4);
                const float fg = sc.y;
                const float w = __fsub_rn(p.z, p.x);
                const float h = __fsub_rn(p.w, p.y);
                if ((fg > 0.5f) && (w >= 16.0f) && (h >= 16.0f)) {
                    k = 0x3F800000u - __float_as_uint(fg);
                    localc++;
                }
            }
            kk[e] = k;
        }
        *reinterpret_cast<uint4*>(&K0[n0]) = make_uint4(kk[0], kk[1], kk[2], kk[3]);
        ushort4 pp;
        pp.x = (unsigned short)(n0 + 0); pp.y = (unsigned short)(n0 + 1);
        pp.z = (unsigned short)(n0 + 2); pp.w = (unsigned short)(n0 + 3);
        *reinterpret_cast<ushort4*>(&P0[n0]) = pp;
    }
    for (int off = 32; off > 0; off >>= 1) localc += __shfl_down(localc, off);
    if ((tid & 63) == 0) atomicAdd(&s_cnt, localc);

    unsigned int kr[EPT];
    unsigned short pr[EPT];

    for (int pass = 0; pass < 6; ++pass) {
        const int shift = pass * 4;
        const unsigned int*   ksrc = (pass & 1) ? K1 : K0;
        unsigned int*         kdst = (pass & 1) ? K0 : K1;
        const unsigned short* psrc = (pass & 1) ? P1 : P0;
        unsigned short*       pdst = (pass & 1) ? P0 : P1;

        // zero hist
        for (int hh = tid; hh < (16 * HP2) / 2; hh += SORT_T)
            reinterpret_cast<unsigned int*>(Hs)[hh] = 0;
        __syncthreads();

        // load this thread's 4 elements (vector LDS reads, conflict-free)
        {
            const uint4 kv = *reinterpret_cast<const uint4*>(&ksrc[tid * EPT]);
            kr[0] = kv.x; kr[1] = kv.y; kr[2] = kv.z; kr[3] = kv.w;
            const ushort4 pv = *reinterpret_cast<const ushort4*>(&psrc[tid * EPT]);
            pr[0] = pv.x; pr[1] = pv.y; pr[2] = pv.z; pr[3] = pv.w;
        }
        // count
        #pragma unroll
        for (int e = 0; e < EPT; ++e) {
            const unsigned int d = (kr[e] >> shift) & 15u;
            Hs[d * HP2 + tid]++;
        }
        __syncthreads();

        // exclusive scan over 16384 counters in digit-major order:
        // thread tid scans global f in [16*tid, 16*tid+16) where
        // f = d*1024 + t  ->  d = tid>>6, t = (tid&63)*16 + e.
        {
            const int d  = tid >> 6;
            const int t0 = (tid & 63) * 16;
            unsigned short* row = &Hs[d * HP2];
            unsigned int sum = 0;
            #pragma unroll
            for (int e = 0; e < 16; ++e) {
                const unsigned int v = row[t0 + e];
                row[t0 + e] = (unsigned short)sum;
                sum += v;
            }
            unsigned int x = sum;
            #pragma unroll
            for (int off = 1; off < 64; off <<= 1) {
                const unsigned int y = __shfl_up(x, off);
                if ((tid & 63) >= off) x += y;
            }
            const int wid = tid >> 6;
            if ((tid & 63) == 63) sWT[wid] = x;
            __syncthreads();
            unsigned int base = x - sum;        // exclusive within wave
            for (int w = 0; w < wid; ++w) base += sWT[w];
            #pragma unroll
            for (int e = 0; e < 16; ++e) row[t0 + e] += (unsigned short)base;
        }
        __syncthreads();

        // stable scatter
        #pragma unroll
        for (int e = 0; e < EPT; ++e) {
            const unsigned int d = (kr[e] >> shift) & 15u;
            const unsigned int pos = Hs[d * HP2 + tid]++;
            kdst[pos] = kr[e];
            pdst[pos] = pr[e];
        }
        __syncthreads();
    }

    const int nv = s_cnt;
    if (tid == 0) g_nvalid[b] = nv;
    {
        const int p0 = tid * EPT;
        const ushort4 pv = *reinterpret_cast<const ushort4*>(&P0[p0]);
        const unsigned short pe[EPT] = {pv.x, pv.y, pv.z, pv.w};
        #pragma unroll
        for (int e = 0; e < EPT; ++e) {
            const int p = p0 + e;
            if (p < nv)
                g_sorted[b][p] = *reinterpret_cast<const float4*>(props + ((size_t)b * NBOX + pe[e]) * 4);
        }
    }
}

// ---------------------------------------------------------------------------
// Kernel 2: suppression bitmask rows (triangular) + diagonal-word tile write.
// XCD-AFFINITY: 1D grid id = i*8 + b -> round-robin puts every block of
// batch b on XCD b, so g_sup/g_tile64 for batch b stay in XCD b's L2 —
// where nms block b runs. (R12-proven: this + Jacobi cut nms to ~13 us.)
// ---------------------------------------------------------------------------
__global__ __launch_bounds__(64) void iou_kernel() {
    const int id = blockIdx.x;
    const int b = id & (BATCH - 1);
    const int i = id >> 3;
    const int nv = g_nvalid[b];
    if (i >= nv) return;
    const int lane = threadIdx.x;
    const int c0 = i >> 6;
    const int W = (nv + 63) >> 6;

    const float4 bi = g_sorted[b][i];
    const float areai = __fmul_rn(__fsub_rn(bi.z, bi.x), __fsub_rn(bi.w, bi.y));

    u64 myword = 0ull;
    for (int c = c0; c < W; ++c) {
        const int j = (c << 6) + lane;
        bool pred = false;
        if (j < nv && j > i) {
            const float4 bj = g_sorted[b][j];
            const float areaj = __fmul_rn(__fsub_rn(bj.z, bj.x), __fsub_rn(bj.w, bj.y));
            const float xi1 = fmaxf(bi.x, bj.x);
            const float yi1 = fmaxf(bi.y, bj.y);
            const float xi2 = fminf(bi.z, bj.z);
            const float yi2 = fminf(bi.w, bj.w);
            const float iw = fmaxf(__fsub_rn(xi2, xi1), 0.0f);
            const float ih = fmaxf(__fsub_rn(yi2, yi1), 0.0f);
            const float inter = __fmul_rn(iw, ih);
            const float uni = __fsub_rn(__fadd_rn(areai, areaj), inter);
            pred = (inter / uni) >= 0.5f;
        }
        const u64 wd = __ballot(pred);
        if (lane == c) myword = wd;
    }
    g_sup[b][i][lane] = myword;
    if (lane == c0) g_tile64[b][c0][i & 63] = myword;
}

// ---------------------------------------------------------------------------
// Kernel 2b: transpose each 64x64 diagonal block (column j, bit r =
// M[64t+r][64t+j]). Same 1D XCD-affinity indexing: id = t*8 + b.
// ---------------------------------------------------------------------------
__global__ __launch_bounds__(64) void colT_kernel() {
    const int id = blockIdx.x;
    const int b = id & (BATCH - 1);
    const int t = id >> 3;          // 0..63
    const int j = threadIdx.x;
    const u64* rw = &g_tile64[b][t][0];
    u64 col = 0ull;
    #pragma unroll
    for (int r = 0; r < 64; ++r)
        col |= ((rw[r] >> j) & 1ull) << r;
    g_colT[b][t][j] = col;
}

// ---------------------------------------------------------------------------
// Kernel 3: greedy scan, one wave per batch, JACOBI-FIXPOINT greedy (R12-
// proven): keep <- alive & ((ballot(keep) & colT) == 0) converges to the
// serial-greedy fixpoint in chain-depth+1 ballots. Kept-index extraction:
// mbcnt rank + LDS scatter (emit) and scalar ctz/clear (OR-load addresses).
// Cross-block OR: batched named-reg loads, L2-local under XCD affinity.
// ---------------------------------------------------------------------------
__device__ __forceinline__ unsigned int rdlu(unsigned int v, int l) {
    return (unsigned int)__builtin_amdgcn_readlane((int)v, l);
}
__device__ __forceinline__ u64 rdl64(u64 v, int l) {
    const unsigned lo = rdlu((unsigned)v, l);
    const unsigned hi = rdlu((unsigned)(v >> 32), l);
    return ((u64)hi << 32) | lo;
}

__global__ __launch_bounds__(64) void nms_kernel(float* __restrict__ out) {
    const int b = blockIdx.x;
    const int lane = threadIdx.x;
    int nv = g_nvalid[b];
    if (nv > NBOX) nv = NBOX;
    float4* outv = reinterpret_cast<float4*>(out) + (size_t)b * MAXK;
    const u64* supb = &g_sup[b][0][0];
    __shared__ int sIdx[64];

    // zero-fill output up-front (off the critical chain)
    for (int s = lane; s < MAXK; s += 64)
        outv[s] = make_float4(0.0f, 0.0f, 0.0f, 0.0f);

    u64 removed = 0ull;                 // lane w holds removed word w
    int kept = 0;
    const int nblk = (nv + 63) >> 6;    // <= 63

    u64 colT = g_colT[b][0][lane];      // column lane of diagonal block 0

    for (int blk = 0; blk < nblk && kept < MAXK; ++blk) {
        const int base = blk << 6;
        // prefetch next block's transposed column (padded array, in-bounds)
        const u64 colT_n = g_colT[b][blk + 1][lane];

        // incoming suppression word for this block (2 readlanes, once/block)
        const u64 wv = rdl64(removed, blk);
        const int alive = (int)((~wv >> lane) & 1ull) & (int)(base + lane < nv);

        // Jacobi fixpoint (ballots only; no per-kept-row serial loop)
        u64 bal = __ballot(alive != 0);
        const unsigned cLo = (unsigned)colT, cHi = (unsigned)(colT >> 32);
        while (bal != 0ull) {
            const unsigned bLo = (unsigned)bal, bHi = (unsigned)(bal >> 32);
            const int sup = (((cLo & bLo) | (cHi & bHi)) != 0u);
            const u64 nb = __ballot((alive & (sup ^ 1)) != 0);
            if (nb == bal) break;
            bal = nb;
        }

        int m = __popcll(bal);
        const int cap = MAXK - kept;
        while (m > cap) {               // rare: only the final block
            bal &= ~(1ull << (63 - __builtin_clzll(bal)));
            --m;
        }

        if (m > 0) {
            // emit (off-chain): rank-compact kept indices via mbcnt + LDS
            unsigned rank = __builtin_amdgcn_mbcnt_lo((unsigned)bal, 0u);
            rank = __builtin_amdgcn_mbcnt_hi((unsigned)(bal >> 32), rank);
            if ((bal >> lane) & 1ull) sIdx[rank] = base + lane;
            const int myIdx = sIdx[lane];      // valid for lane < m
            if (lane < m) outv[kept + lane] = g_sorted[b][myIdx];

            // batched OR of kept rows' full suppression rows (scalar-extracted
            // addresses; loads L2-local under XCD affinity; ONE drain/group)
            if (kept + m < MAXK && blk + 1 < nblk) {
                u64 balT = bal;
                for (int t = 0; t < m; t += 32) {
#define LDW(j) u64 v##j = 0ull; {                                               \
                        if (t + j < m) {                                        \
                            const int it = base + __builtin_ctzll(balT);        \
                            balT &= balT - 1ull;                                \
                            v##j = supb[(size_t)it * WPR + lane];               \
                        } }
                    LDW(0)  LDW(1)  LDW(2)  LDW(3)  LDW(4)  LDW(5)  LDW(6)  LDW(7)
                    LDW(8)  LDW(9)  LDW(10) LDW(11) LDW(12) LDW(13) LDW(14) LDW(15)
                    LDW(16) LDW(17) LDW(18) LDW(19) LDW(20) LDW(21) LDW(22) LDW(23)
                    LDW(24) LDW(25) LDW(26) LDW(27) LDW(28) LDW(29) LDW(30) LDW(31)
#undef LDW
                    const u64 o0 = ((v0 | v1) | (v2 | v3)) | ((v4 | v5) | (v6 | v7));
                    const u64 o1 = ((v8 | v9) | (v10 | v11)) | ((v12 | v13) | (v14 | v15));
                    const u64 o2 = ((v16 | v17) | (v18 | v19)) | ((v20 | v21) | (v22 | v23));
                    const u64 o3 = ((v24 | v25) | (v26 | v27)) | ((v28 | v29) | (v30 | v31));
                    removed |= (o0 | o1) | (o2 | o3);
                }
            }
            kept += m;
        }
        colT = colT_n;
    }
}

extern "C" void kernel_launch(void* const* d_in, const int* in_sizes, int n_in,
                              void* d_out, int out_size, void* d_ws, size_t ws_size,
                              hipStream_t stream) {
    const float* props  = (const float*)d_in[0];   // (8,4000,4) f32
    const float* scores = (const float*)d_in[1];   // (8,4000,2) f32
    float* out = (float*)d_out;                    // (8,300,4) f32

    sort_kernel<<<BATCH, SORT_T, 0, stream>>>(props, scores);
    iou_kernel<<<NBOX * BATCH, 64, 0, stream>>>();        // id = i*8 + b
    colT_kernel<<<64 * BATCH, 64, 0, stream>>>();         // id = t*8 + b
    nms_kernel<<<BATCH, 64, 0, stream>>>(out);
}

// Round 14
// 59.581 us; speedup vs baseline: 1.0700x; 1.0700x over previous
//
#include <hip/hip_runtime.h>

#define NBOX 4000
#define NPAD 4096
#define BATCH 8
#define WPR 64          // 64-bit words per suppression row
#define MAXK 300

typedef unsigned long long u64;

// Static device scratch (deterministic: every consulted value is rewritten
// each call — g_colT is zeroed in sort_kernel before iou ORs into it).
__device__ u64 g_sup[BATCH][NPAD][WPR];            // ~16.8 MB full rows
__device__ u64 g_colT[BATCH][65][64];              // transposed diag blocks
__device__ float4 g_sorted[BATCH][NPAD];           // sorted boxes + sentinels
__device__ float g_area[BATCH][NPAD];              // precomputed areas (0 for pad)
__device__ int g_nvalid[BATCH];

// ---------------------------------------------------------------------------
// Kernel 1: per-batch stable LSD radix sort, 1024 threads x EPT=4 (R13).
// Key k = 0x3F800000 - bits(fg): valid => fg > 0.5 => k in (0, 0x800000),
// fits 24 bits -> 6 passes x 4 bits. Invalid/pad k = 0xFFFFFF sorts last.
// Blocked ownership + digit-major scan preserves jnp.argsort stability.
// Epilogue: writes sorted boxes, SENTINEL boxes (2e9) for p >= nv (makes
// iou's j<nv guard unnecessary: iw=0, areaj=0 => pred false exactly),
// per-box areas (same __f*_rn ops as reference), and zeroes g_colT.
// ---------------------------------------------------------------------------
#define SORT_T 1024
#define EPT 4
#define HP2 1088        // hist pitch (u16 entries per digit row)

__global__ __launch_bounds__(SORT_T) void sort_kernel(const float* __restrict__ props,
                                                      const float* __restrict__ scores) {
    const int b = blockIdx.x;
    const int tid = threadIdx.x;
    __shared__ unsigned int K0[NPAD], K1[NPAD];        // 32 KB
    __shared__ unsigned short P0[NPAD], P1[NPAD];      // 16 KB
    __shared__ unsigned short Hs[16 * HP2];            // 34 KB
    __shared__ unsigned int sWT[16];
    __shared__ int s_cnt;
    if (tid == 0) s_cnt = 0;
    __syncthreads();

    // Build keys + payloads (blocked: thread t owns n in [4t, 4t+3]).
    int localc = 0;
    {
        const int n0 = tid * EPT;
        unsigned int kk[EPT];
        #pragma unroll
        for (int e = 0; e < EPT; ++e) {
            const int n = n0 + e;
            unsigned int k = 0xFFFFFFu;
            if (n < NBOX) {
                const float2 sc = *reinterpret_cast<const float2*>(scores + ((size_t)b * NBOX + n) * 2);
                const float4 p  = *reinterpret_cast<const float4*>(props  + ((size_t)b * NBOX + n) * 4);
                const float fg = sc.y;
                const float w = __fsub_rn(p.z, p.x);
                const float h = __fsub_rn(p.w, p.y);
                if ((fg > 0.5f) && (w >= 16.0f) && (h >= 16.0f)) {
                    k = 0x3F800000u - __float_as_uint(fg);
                    localc++;
                }
            }
            kk[e] = k;
        }
        *reinterpret_cast<uint4*>(&K0[n0]) = make_uint4(kk[0], kk[1], kk[2], kk[3]);
        ushort4 pp;
        pp.x = (unsigned short)(n0 + 0); pp.y = (unsigned short)(n0 + 1);
        pp.z = (unsigned short)(n0 + 2); pp.w = (unsigned short)(n0 + 3);
        *reinterpret_cast<ushort4*>(&P0[n0]) = pp;
    }
    for (int off = 32; off > 0; off >>= 1) localc += __shfl_down(localc, off);
    if ((tid & 63) == 0) atomicAdd(&s_cnt, localc);

    unsigned int kr[EPT];
    unsigned short pr[EPT];

    for (int pass = 0; pass < 6; ++pass) {
        const int shift = pass * 4;
        const unsigned int*   ksrc = (pass & 1) ? K1 : K0;
        unsigned int*         kdst = (pass & 1) ? K0 : K1;
        const unsigned short* psrc = (pass & 1) ? P1 : P0;
        unsigned short*       pdst = (pass & 1) ? P0 : P1;

        for (int hh = tid; hh < (16 * HP2) / 2; hh += SORT_T)
            reinterpret_cast<unsigned int*>(Hs)[hh] = 0;
        __syncthreads();

        {
            const uint4 kv = *reinterpret_cast<const uint4*>(&ksrc[tid * EPT]);
            kr[0] = kv.x; kr[1] = kv.y; kr[2] = kv.z; kr[3] = kv.w;
            const ushort4 pv = *reinterpret_cast<const ushort4*>(&psrc[tid * EPT]);
            pr[0] = pv.x; pr[1] = pv.y; pr[2] = pv.z; pr[3] = pv.w;
        }
        #pragma unroll
        for (int e = 0; e < EPT; ++e) {
            const unsigned int d = (kr[e] >> shift) & 15u;
            Hs[d * HP2 + tid]++;
        }
        __syncthreads();

        // digit-major exclusive scan over 16384 counters
        {
            const int d  = tid >> 6;
            const int t0 = (tid & 63) * 16;
            unsigned short* row = &Hs[d * HP2];
            unsigned int sum = 0;
            #pragma unroll
            for (int e = 0; e < 16; ++e) {
                const unsigned int v = row[t0 + e];
                row[t0 + e] = (unsigned short)sum;
                sum += v;
            }
            unsigned int x = sum;
            #pragma unroll
            for (int off = 1; off < 64; off <<= 1) {
                const unsigned int y = __shfl_up(x, off);
                if ((tid & 63) >= off) x += y;
            }
            const int wid = tid >> 6;
            if ((tid & 63) == 63) sWT[wid] = x;
            __syncthreads();
            unsigned int base = x - sum;        // exclusive within wave
            for (int w = 0; w < wid; ++w) base += sWT[w];
            #pragma unroll
            for (int e = 0; e < 16; ++e) row[t0 + e] += (unsigned short)base;
        }
        __syncthreads();

        #pragma unroll
        for (int e = 0; e < EPT; ++e) {
            const unsigned int d = (kr[e] >> shift) & 15u;
            const unsigned int pos = Hs[d * HP2 + tid]++;
            kdst[pos] = kr[e];
            pdst[pos] = pr[e];
        }
        __syncthreads();
    }

    const int nv = s_cnt;
    if (tid == 0) g_nvalid[b] = nv;
    {
        const int p0 = tid * EPT;
        const ushort4 pv = *reinterpret_cast<const ushort4*>(&P0[p0]);
        const unsigned short pe[EPT] = {pv.x, pv.y, pv.z, pv.w};
        #pragma unroll
        for (int e = 0; e < EPT; ++e) {
            const int p = p0 + e;
            if (p < nv) {
                const float4 bx = *reinterpret_cast<const float4*>(props + ((size_t)b * NBOX + pe[e]) * 4);
                g_sorted[b][p] = bx;
                g_area[b][p] = __fmul_rn(__fsub_rn(bx.z, bx.x), __fsub_rn(bx.w, bx.y));
            } else {
                g_sorted[b][p] = make_float4(2e9f, 2e9f, 2e9f, 2e9f);
                g_area[b][p] = 0.0f;
            }
        }
    }
    // zero this batch's colT (consumed by iou's atomicOr, then nms)
    for (int z = tid; z < 65 * 64; z += SORT_T)
        (&g_colT[b][0][0])[z] = 0ull;
}

// ---------------------------------------------------------------------------
// Kernel 2: suppression bitmask rows (triangular) + FUSED colT scatter.
// XCD-AFFINITY 1D grid id = i*8 + b (R12-proven). The peeled c==c0
// iteration keeps the j>i guard; for c>c0, j>i holds identically, and the
// j<nv guard is gone (sentinel boxes yield pred=false exactly: iw=0,
// areaj=0 => inter/uni = 0/areai = 0 < 0.5). At c==c0 every lane already
// holds the full diagonal word wd (ballot), so lane j ORs its bit into the
// transposed column g_colT[b][c0][j] directly — no separate colT kernel.
// OR is commutative => order-independent => deterministic.
// ---------------------------------------------------------------------------
__global__ __launch_bounds__(64) void iou_kernel() {
    const int id = blockIdx.x;
    const int b = id & (BATCH - 1);
    const int i = id >> 3;
    const int nv = g_nvalid[b];
    if (i >= nv) return;
    const int lane = threadIdx.x;
    const int c0 = i >> 6;
    const int W = (nv + 63) >> 6;

    const float4 bi = g_sorted[b][i];
    const float areai = g_area[b][i];

    u64 myword = 0ull;
    // peeled diagonal chunk c = c0 (the only chunk needing j > i)
    {
        const int j = (c0 << 6) + lane;
        const float4 bj = g_sorted[b][j];
        const float areaj = g_area[b][j];
        const float xi1 = fmaxf(bi.x, bj.x);
        const float yi1 = fmaxf(bi.y, bj.y);
        const float xi2 = fminf(bi.z, bj.z);
        const float yi2 = fminf(bi.w, bj.w);
        const float iw = fmaxf(__fsub_rn(xi2, xi1), 0.0f);
        const float ih = fmaxf(__fsub_rn(yi2, yi1), 0.0f);
        const float inter = __fmul_rn(iw, ih);
        const float uni = __fsub_rn(__fadd_rn(areai, areaj), inter);
        const bool pred = ((inter / uni) >= 0.5f) && (j > i);
        const u64 wd = __ballot(pred);
        if (lane == c0) myword = wd;
        // fused transposed-column scatter: lane j owns column j of tile c0
        const u64 contrib = ((wd >> lane) & 1ull) << (i & 63);
        if (contrib) atomicOr(&g_colT[b][c0][lane], contrib);
    }
    // off-diagonal chunks: j > i automatic, sentinels handle j >= nv
    for (int c = c0 + 1; c < W; ++c) {
        const int j = (c << 6) + lane;
        const float4 bj = g_sorted[b][j];
        const float areaj = g_area[b][j];
        const float xi1 = fmaxf(bi.x, bj.x);
        const float yi1 = fmaxf(bi.y, bj.y);
        const float xi2 = fminf(bi.z, bj.z);
        const float yi2 = fminf(bi.w, bj.w);
        const float iw = fmaxf(__fsub_rn(xi2, xi1), 0.0f);
        const float ih = fmaxf(__fsub_rn(yi2, yi1), 0.0f);
        const float inter = __fmul_rn(iw, ih);
        const float uni = __fsub_rn(__fadd_rn(areai, areaj), inter);
        const bool pred = (inter / uni) >= 0.5f;
        const u64 wd = __ballot(pred);
        if (lane == c) myword = wd;
    }
    g_sup[b][i][lane] = myword;
}

// ---------------------------------------------------------------------------
// Kernel 3: greedy scan, one wave per batch, JACOBI-FIXPOINT greedy (R12-
// proven). Kept-index extraction now fully via sIdx (mbcnt rank + LDS
// scatter): the OR-load addresses are parallel broadcast LDS reads instead
// of the former 32-step serial ctz/clear chain. Cross-block OR: batched
// named-reg loads, L2-local under XCD affinity, ONE drain per group.
// ---------------------------------------------------------------------------
__device__ __forceinline__ unsigned int rdlu(unsigned int v, int l) {
    return (unsigned int)__builtin_amdgcn_readlane((int)v, l);
}
__device__ __forceinline__ u64 rdl64(u64 v, int l) {
    const unsigned lo = rdlu((unsigned)v, l);
    const unsigned hi = rdlu((unsigned)(v >> 32), l);
    return ((u64)hi << 32) | lo;
}

__global__ __launch_bounds__(64) void nms_kernel(float* __restrict__ out) {
    const int b = blockIdx.x;
    const int lane = threadIdx.x;
    int nv = g_nvalid[b];
    if (nv > NBOX) nv = NBOX;
    float4* outv = reinterpret_cast<float4*>(out) + (size_t)b * MAXK;
    const u64* supb = &g_sup[b][0][0];
    __shared__ int sIdx[64];

    // zero-fill output up-front (off the critical chain)
    for (int s = lane; s < MAXK; s += 64)
        outv[s] = make_float4(0.0f, 0.0f, 0.0f, 0.0f);

    u64 removed = 0ull;                 // lane w holds removed word w
    int kept = 0;
    const int nblk = (nv + 63) >> 6;    // <= 63

    u64 colT = g_colT[b][0][lane];      // column lane of diagonal block 0

    for (int blk = 0; blk < nblk && kept < MAXK; ++blk) {
        const int base = blk << 6;
        // prefetch next block's transposed column (padded array, in-bounds)
        const u64 colT_n = g_colT[b][blk + 1][lane];

        // incoming suppression word for this block (2 readlanes, once/block)
        const u64 wv = rdl64(removed, blk);
        const int alive = (int)((~wv >> lane) & 1ull) & (int)(base + lane < nv);

        // Jacobi fixpoint (ballots only; no per-kept-row serial loop)
        u64 bal = __ballot(alive != 0);
        const unsigned cLo = (unsigned)colT, cHi = (unsigned)(colT >> 32);
        while (bal != 0ull) {
            const unsigned bLo = (unsigned)bal, bHi = (unsigned)(bal >> 32);
            const int sup = (((cLo & bLo) | (cHi & bHi)) != 0u);
            const u64 nb = __ballot((alive & (sup ^ 1)) != 0);
            if (nb == bal) break;
            bal = nb;
        }

        int m = __popcll(bal);
        const int cap = MAXK - kept;
        while (m > cap) {               // rare: only the final block
            bal &= ~(1ull << (63 - __builtin_clzll(bal)));
            --m;
        }

        if (m > 0) {
            // rank-compact kept indices via mbcnt + LDS (same-wave, no barrier)
            unsigned rank = __builtin_amdgcn_mbcnt_lo((unsigned)bal, 0u);
            rank = __builtin_amdgcn_mbcnt_hi((unsigned)(bal >> 32), rank);
            if ((bal >> lane) & 1ull) sIdx[rank] = base + lane;
            const int myIdx = sIdx[lane];      // valid for lane < m
            if (lane < m) outv[kept + lane] = g_sorted[b][myIdx];

            // batched OR of kept rows' full suppression rows; addresses come
            // from parallel sIdx broadcast reads (not a serial ctz chain)
            if (kept + m < MAXK && blk + 1 < nblk) {
                for (int t = 0; t < m; t += 32) {
#define LDW(j) u64 v##j; {                                                      \
                        int tt = t + j; if (tt >= m) tt = m - 1;                \
                        const int it = sIdx[tt];                                \
                        v##j = supb[(size_t)it * WPR + lane];                   }
                    LDW(0)  LDW(1)  LDW(2)  LDW(3)  LDW(4)  LDW(5)  LDW(6)  LDW(7)
                    LDW(8)  LDW(9)  LDW(10) LDW(11) LDW(12) LDW(13) LDW(14) LDW(15)
                    LDW(16) LDW(17) LDW(18) LDW(19) LDW(20) LDW(21) LDW(22) LDW(23)
                    LDW(24) LDW(25) LDW(26) LDW(27) LDW(28) LDW(29) LDW(30) LDW(31)
#undef LDW
                    const u64 o0 = ((v0 | v1) | (v2 | v3)) | ((v4 | v5) | (v6 | v7));
                    const u64 o1 = ((v8 | v9) | (v10 | v11)) | ((v12 | v13) | (v14 | v15));
                    const u64 o2 = ((v16 | v17) | (v18 | v19)) | ((v20 | v21) | (v22 | v23));
                    const u64 o3 = ((v24 | v25) | (v26 | v27)) | ((v28 | v29) | (v30 | v31));
                    removed |= (o0 | o1) | (o2 | o3);
                }
            }
            kept += m;
        }
        colT = colT_n;
    }
}

extern "C" void kernel_launch(void* const* d_in, const int* in_sizes, int n_in,
                              void* d_out, int out_size, void* d_ws, size_t ws_size,
                              hipStream_t stream) {
    const float* props  = (const float*)d_in[0];   // (8,4000,4) f32
    const float* scores = (const float*)d_in[1];   // (8,4000,2) f32
    float* out = (float*)d_out;                    // (8,300,4) f32

    sort_kernel<<<BATCH, SORT_T, 0, stream>>>(props, scores);
    iou_kernel<<<NBOX * BATCH, 64, 0, stream>>>();        // id = i*8 + b
    nms_kernel<<<BATCH, 64, 0, stream>>>(out);
}